// Round 16
// baseline (1398.275 us; speedup 1.0000x reference)
//
#include <hip/hip_runtime.h>

typedef __attribute__((ext_vector_type(8))) short bf16x8;
typedef __attribute__((ext_vector_type(4))) float fx4;
typedef __attribute__((ext_vector_type(4))) unsigned short u16x4;
typedef __attribute__((ext_vector_type(8))) unsigned short u16x8;
typedef __attribute__((ext_vector_type(4))) unsigned int u32x4;

#define DEV static __device__ __forceinline__

DEV unsigned short f2bf(float f) {
  union { float f; unsigned u; } v; v.f = f;
  unsigned u = v.u;
  u += 0x7fffu + ((u >> 16) & 1u);
  return (unsigned short)(u >> 16);
}
DEV unsigned pk(float a, float b) { return (unsigned)f2bf(a) | ((unsigned)f2bf(b) << 16); }
DEV float sigm(float x) { return 1.f / (1.f + __expf(-x)); }

// coalesced 16B load bypassing (possibly stale) L1/L2, served at MALL.
DEV u32x4 load_coh16(const void* p) {
  u32x4 r;
  asm volatile("global_load_dwordx4 %0, %1, off sc0 sc1" : "=v"(r) : "v"(p));
  return r;
}

// async global->LDS 16B (m97 staging path)
typedef __attribute__((address_space(1))) const unsigned int guint;
typedef __attribute__((address_space(3))) unsigned int luint;
DEV void gload_lds16(const void* g, void* l) {
  __builtin_amdgcn_global_load_lds((guint*)g, (luint*)l, 16, 0, 0);
}

// ---------- dual embedding gather -> bf16, dst row r = t*32 + b ----------
__global__ void k_gather2(const float* __restrict__ embE, const int* __restrict__ tokE,
                          unsigned short* __restrict__ dstE,
                          const float* __restrict__ embC, const int* __restrict__ tokC,
                          unsigned short* __restrict__ dstC) {
  int bid = blockIdx.x;
  int r = bid & 2047;
  const float* emb = bid < 2048 ? embE : embC;
  const int* tok = bid < 2048 ? tokE : tokC;
  unsigned short* dst = bid < 2048 ? dstE : dstC;
  int t = r >> 5, b = r & 31;
  int token = tok[b * 64 + t];  // tok is [B=32][T=64]
  const fx4* srow = (const fx4*)(emb + (long)token * 1024);
  u16x4* drow = (u16x4*)(dst + (long)r * 1024);
  fx4 v = srow[threadIdx.x];
  u16x4 o = { f2bf(v[0]), f2bf(v[1]), f2bf(v[2]), f2bf(v[3]) };
  drow[threadIdx.x] = o;
}

// ---------- init: zero tagged h buffer (tags must start < 1) + lengths ----------
__global__ void k_init(const int* __restrict__ mask, int* __restrict__ sel,
                       unsigned* __restrict__ hbufT) {
  int i = blockIdx.x * 256 + threadIdx.x;  // grid 64 -> 16384 threads x 4 u32
  u32x4 z = {0u, 0u, 0u, 0u};
  ((u32x4*)hbufT)[i] = z;
  if (blockIdx.x == 0 && threadIdx.x < 32) {
    int t = threadIdx.x, s = 0;
    for (int k = 0; k < 64; ++k) s += mask[t * 64 + k];
    sel[t] = (s + 63) & 63;  // (sum-1) with jnp negative-index wrap
  }
}

// ---------- dual fp32 -> bf16 convert (WihE + WihD) ----------
__global__ void k_f2bf_dual(const float* __restrict__ s0, unsigned short* __restrict__ d0,
                            const float* __restrict__ s1, unsigned short* __restrict__ d1,
                            long n4) {
  const float* s = blockIdx.x < 1024 ? s0 : s1;
  unsigned short* d = blockIdx.x < 1024 ? d0 : d1;
  long base = (long)(blockIdx.x & 1023) * 256 + threadIdx.x;
  for (long i = base; i < n4; i += 1024 * 256) {
    fx4 v = ((const fx4*)s)[i];
    u16x4 o = { f2bf(v[0]), f2bf(v[1]), f2bf(v[2]), f2bf(v[3]) };
    ((u16x4*)d)[i] = o;
  }
}

// ============================================================================
// MERGED persistent LSTM scan with TAGGED h exchange (flag == data).
// 64 scan blocks x 512 threads, 1 block/CU. Block owns 16 j's (XCD-swizzled).
// h element = u32 (bf16(h)<<16 | gen). Step s (s>=1) stages buf[s&1], polling
// tag >= s on the data itself — one MALL round trip, no separate barrier.
// Double buffer + per-buffer gens stepping by 2 make overwrite race-free
// (writer of s+1 has read all s -> all blocks wrote s -> all read s-1).
// Encoder s=0..63 (gens 1..64; s=63 writes HSEL tagged 64 = decoder input),
// decoder s=64..127 (gens 65..127). Whh frags in registers per phase.
// Blocks >=64: Wout fp32->bf16 convert on idle CUs, then retire.
// ============================================================================
#define SCAN_NBLK 64

__global__ __launch_bounds__(512) void k_scan_all(
    const float* __restrict__ WhhE, const float* __restrict__ bhhE,
    const float* __restrict__ xg_e,
    const float* __restrict__ WhhD, const float* __restrict__ bhhD,
    const float* __restrict__ xg_d,
    const float* __restrict__ h0, const float* __restrict__ c0,
    unsigned* __restrict__ hbufT,         // [2][32][1024] u32 tagged
    const int* __restrict__ sel,
    float* __restrict__ hid_out,          // [32][64][1024] fp32 (decoder out)
    unsigned short* __restrict__ hid_bf,  // [2048][1024] bf16 b-major (optional)
    const float* __restrict__ wsrc,       // convert source (optional)
    unsigned short* __restrict__ wdst,    // convert dest
    long wn4) {
  int tid = threadIdx.x;
  int bid = blockIdx.x;
  if (bid >= SCAN_NBLK) {  // spare blocks: Wout convert on idle CUs, then exit
    long i = (long)(bid - SCAN_NBLK) * 512 + tid;
    long st = (long)(gridDim.x - SCAN_NBLK) * 512;
    for (; i < wn4; i += st) {
      fx4 v = ((const fx4*)wsrc)[i];
      u16x4 o = { f2bf(v[0]), f2bf(v[1]), f2bf(v[2]), f2bf(v[3]) };
      ((u16x4*)wdst)[i] = o;
    }
    return;
  }
  __shared__ __align__(16) unsigned short hlds[49152];  // 96 KB decl (64 used)
  __shared__ float gbuf[4][32][16];                     // 8 KB
  int j0 = ((bid & 7) * 8 + (bid >> 3)) * 16;  // XCD-contiguous 128-j band
  int w = tid >> 6, lane = tid & 63;
  int mt = w & 1, nt = w >> 1;          // batch half (2) x gate tile (4)
  int fr = lane & 15, fg = lane >> 4;

  auto loadBreg = [&](const float* Whh, bf16x8* breg) {
    const float* wrow = Whh + ((long)(nt * 1024 + j0 + fr) << 10);
#pragma unroll
    for (int i = 0; i < 32; ++i) {
      int kc = i * 4 + fg;
      fx4 lo = *(const fx4*)(wrow + kc * 8);
      fx4 hi = *(const fx4*)(wrow + kc * 8 + 4);
      bf16x8 o = { (short)f2bf(lo[0]), (short)f2bf(lo[1]), (short)f2bf(lo[2]), (short)f2bf(lo[3]),
                   (short)f2bf(hi[0]), (short)f2bf(hi[1]), (short)f2bf(hi[2]), (short)f2bf(hi[3]) };
      breg[i] = o;
    }
  };

  // tagged stage for global step s (s >= 1): poll tag >= s on the data
  int colb = (tid & 255) * 4;
  int kcs = colb >> 3, sub = (colb & 7) * 2;  // LDS sub-offset 0 or 8 bytes
  auto stage_tagged = [&](int s) {
    const unsigned* src = hbufT + (s & 1) * 32768;
    u32x4 hv[16];
#pragma unroll
    for (int it = 0; it < 16; ++it)
      hv[it] = load_coh16(src + it * 2048 + tid * 4);
    asm volatile("s_waitcnt vmcnt(0)" ::: "memory");
    unsigned stale = 0;
#pragma unroll
    for (int it = 0; it < 16; ++it) {
      unsigned bad = 0;
#pragma unroll
      for (int e = 0; e < 4; ++e) bad |= ((hv[it][e] & 0xffffu) < (unsigned)s) ? 1u : 0u;
      stale |= bad << it;
    }
    while (stale) {
      __builtin_amdgcn_s_sleep(1);
      for (int it = 0; it < 16; ++it)
        if (stale & (1u << it))
          hv[it] = load_coh16(src + it * 2048 + tid * 4);
      asm volatile("s_waitcnt vmcnt(0)" ::: "memory");
      unsigned ns = 0;
      for (int it = 0; it < 16; ++it) {
        if (stale & (1u << it)) {
          unsigned bad = 0;
          for (int e = 0; e < 4; ++e) bad |= ((hv[it][e] & 0xffffu) < (unsigned)s) ? 1u : 0u;
          ns |= bad << it;
        }
      }
      stale = ns;
    }
    __builtin_amdgcn_sched_barrier(0);
#pragma unroll
    for (int it = 0; it < 16; ++it) {
      int row = it * 2 + (tid >> 8);
      u16x4 o = { (unsigned short)(hv[it][0] >> 16), (unsigned short)(hv[it][1] >> 16),
                  (unsigned short)(hv[it][2] >> 16), (unsigned short)(hv[it][3] >> 16) };
      *(u16x4*)((char*)hlds + (row * 128 + (kcs ^ (row & 31))) * 16 + sub) = o;
    }
  };

  bf16x8 breg[32];
  loadBreg(WhhE, breg);

  // per-thread state: 512 threads = 32 b x 16 j
  int b = tid >> 4, jj = tid & 15, j = j0 + jj;
  float bh0 = bhhE[j], bh1 = bhhE[1024 + j], bh2 = bhhE[2048 + j], bh3 = bhhE[3072 + j];
  float c_reg = c0[b * 1024 + j];
  int sel_b = sel[b];
  float hsel_reg = 0.f, csel_reg = 0.f;
  const float* xp0 = xg_e + (long)b * 4096 + j;
  float x0 = xp0[0], x1 = xp0[1024], x2 = xp0[2048], x3 = xp0[3072];

  // ================= encoder: global steps s = 0..63 =================
  for (int t = 0; t < 64; ++t) {
    if (t == 0) {  // stage from fp32 h0 (no tags)
#pragma unroll
      for (int it = 0; it < 8; ++it) {
        int c = it * 512 + tid;
        const float* src = h0 + (long)c * 8;
        fx4 lo = *(const fx4*)src;
        fx4 hi = *(const fx4*)(src + 4);
        int row = c >> 7, kc = c & 127;
        u16x8 o = { f2bf(lo[0]), f2bf(lo[1]), f2bf(lo[2]), f2bf(lo[3]),
                    f2bf(hi[0]), f2bf(hi[1]), f2bf(hi[2]), f2bf(hi[3]) };
        *(u16x8*)&hlds[(row * 128 + (kc ^ (row & 31))) * 8] = o;
      }
    } else {
      stage_tagged(t);
    }
    __syncthreads();

    int arow = mt * 16 + fr;
    fx4 acca = {0.f, 0.f, 0.f, 0.f}, accb = {0.f, 0.f, 0.f, 0.f};
#pragma unroll
    for (int i = 0; i < 32; i += 2) {
      int kcA = i * 4 + fg, kcB = (i + 1) * 4 + fg;
      bf16x8 a0 = *(const bf16x8*)&hlds[(arow * 128 + (kcA ^ (arow & 31))) * 8];
      bf16x8 a1 = *(const bf16x8*)&hlds[(arow * 128 + (kcB ^ (arow & 31))) * 8];
      acca = __builtin_amdgcn_mfma_f32_16x16x32_bf16(a0, breg[i], acca, 0, 0, 0);
      accb = __builtin_amdgcn_mfma_f32_16x16x32_bf16(a1, breg[i + 1], accb, 0, 0, 0);
    }
#pragma unroll
    for (int q = 0; q < 4; ++q)
      gbuf[nt][mt * 16 + fg * 4 + q][fr] = acca[q] + accb[q];
    __syncthreads();

    {
      float gi = gbuf[0][b][jj] + bh0 + x0;
      float gf = gbuf[1][b][jj] + bh1 + x1;
      float gg = gbuf[2][b][jj] + bh2 + x2;
      float go = gbuf[3][b][jj] + bh3 + x3;
      float c_new = sigm(gf) * c_reg + sigm(gi) * tanhf(gg);
      float h = sigm(go) * tanhf(c_new);
      c_reg = c_new;
      if (t == sel_b) { hsel_reg = h; csel_reg = c_new; }
      // write tagged input for step t+1 (s=63 publishes HSEL = decoder input)
      float hw = (t == 63) ? hsel_reg : h;
      unsigned val = ((unsigned)f2bf(hw) << 16) | (unsigned)(t + 1);
      __hip_atomic_store(&hbufT[((t + 1) & 1) * 32768 + b * 1024 + j], val,
                         __ATOMIC_RELAXED, __HIP_MEMORY_SCOPE_AGENT);
    }

    // prefetch next step's xg (hides under next stage's poll)
    const float* xp = (t < 63) ? (xg_e + (long)(t + 1) * 131072 + (long)b * 4096 + j)
                               : (xg_d + (long)b * 4096 + j);
    x0 = xp[0]; x1 = xp[1024]; x2 = xp[2048]; x3 = xp[3072];
  }

  // ================= handoff (local only) =================
  loadBreg(WhhD, breg);
  bh0 = bhhD[j]; bh1 = bhhD[1024 + j]; bh2 = bhhD[2048 + j]; bh3 = bhhD[3072 + j];
  c_reg = csel_reg;

  // ================= decoder: global steps s = 64..127 =================
  for (int t2 = 0; t2 < 64; ++t2) {
    stage_tagged(64 + t2);
    __syncthreads();

    int arow = mt * 16 + fr;
    fx4 acca = {0.f, 0.f, 0.f, 0.f}, accb = {0.f, 0.f, 0.f, 0.f};
#pragma unroll
    for (int i = 0; i < 32; i += 2) {
      int kcA = i * 4 + fg, kcB = (i + 1) * 4 + fg;
      bf16x8 a0 = *(const bf16x8*)&hlds[(arow * 128 + (kcA ^ (arow & 31))) * 8];
      bf16x8 a1 = *(const bf16x8*)&hlds[(arow * 128 + (kcB ^ (arow & 31))) * 8];
      acca = __builtin_amdgcn_mfma_f32_16x16x32_bf16(a0, breg[i], acca, 0, 0, 0);
      accb = __builtin_amdgcn_mfma_f32_16x16x32_bf16(a1, breg[i + 1], accb, 0, 0, 0);
    }
#pragma unroll
    for (int q = 0; q < 4; ++q)
      gbuf[nt][mt * 16 + fg * 4 + q][fr] = acca[q] + accb[q];
    __syncthreads();

    {
      float gi = gbuf[0][b][jj] + bh0 + x0;
      float gf = gbuf[1][b][jj] + bh1 + x1;
      float gg = gbuf[2][b][jj] + bh2 + x2;
      float go = gbuf[3][b][jj] + bh3 + x3;
      float c_new = sigm(gf) * c_reg + sigm(gi) * tanhf(gg);
      float h = sigm(go) * tanhf(c_new);
      c_reg = c_new;
      int s = 64 + t2;
      if (t2 < 63) {
        unsigned val = ((unsigned)f2bf(h) << 16) | (unsigned)(s + 1);
        __hip_atomic_store(&hbufT[((s + 1) & 1) * 32768 + b * 1024 + j], val,
                           __ATOMIC_RELAXED, __HIP_MEMORY_SCOPE_AGENT);
      }
      long o = ((long)b * 64 + t2) * 1024 + j;
      hid_out[o] = h;
      if (hid_bf) hid_bf[o] = f2bf(h);  // plain store; read next kernel
    }

    if (t2 < 63) {
      const float* xp = xg_d + (long)(t2 + 1) * 131072 + (long)b * 4096 + j;
      x0 = xp[0]; x1 = xp[1024]; x2 = xp[2048]; x3 = xp[3072];
    }
  }
}

// ============================================================================
// Dual pre-gate GEMM (m97 + both-sides swizzle): blocks 0..511 -> set 0,
// 512..1023 -> set 1. (R12 proven, unchanged)
// ============================================================================
__global__ __launch_bounds__(256) void k_gemm_dual(
    const unsigned short* __restrict__ A0, const unsigned short* __restrict__ B0,
    const float* __restrict__ bias0, float* __restrict__ C0,
    const unsigned short* __restrict__ A1, const unsigned short* __restrict__ B1,
    const float* __restrict__ bias1, float* __restrict__ C1) {
  __shared__ __align__(16) unsigned short As[2][4096];
  __shared__ __align__(16) unsigned short Bs[2][4096];
  int lid = blockIdx.x;
  int half = lid >> 9, l = lid & 511;
  const unsigned short* A = half ? A1 : A0;
  const unsigned short* Bw = half ? B1 : B0;
  const float* bias = half ? bias1 : bias0;
  float* C = half ? C1 : C0;
  int swz = (l & 7) * 64 + (l >> 3);
  long m0 = (long)(swz & 15) * 128;
  long n0 = (long)(swz >> 4) * 128;
  int tid = threadIdx.x, lane = tid & 63, w = tid >> 6;
  int mw = (w & 1) * 64, nw = (w >> 1) * 64;
  int fr = lane & 15, fg = lane >> 4;
  fx4 acc[4][4] = {};
  int c0 = tid, c1 = tid + 256;
  int r0 = c0 >> 2, k0s = (c0 & 3) ^ ((r0 >> 1) & 3);
  int r1 = c1 >> 2, k1s = (c1 & 3) ^ ((r1 >> 1) & 3);
  const unsigned short* gA0 = A + (m0 + r0) * 1024 + k0s * 8;
  const unsigned short* gA1 = A + (m0 + r1) * 1024 + k1s * 8;
  const unsigned short* gB0 = Bw + (n0 + r0) * 1024 + k0s * 8;
  const unsigned short* gB1 = Bw + (n0 + r1) * 1024 + k1s * 8;
  auto stage = [&](int buf, int kt) {
    int k0 = kt * 32;
    gload_lds16(gA0 + k0, &As[buf][c0 * 8]);
    gload_lds16(gA1 + k0, &As[buf][c1 * 8]);
    gload_lds16(gB0 + k0, &Bs[buf][c0 * 8]);
    gload_lds16(gB1 + k0, &Bs[buf][c1 * 8]);
  };
  stage(0, 0);
  __syncthreads();
  for (int kt = 0; kt < 32; ++kt) {
    int cur = kt & 1;
    if (kt < 31) stage(cur ^ 1, kt + 1);
    bf16x8 af[4], bfr[4];
#pragma unroll
    for (int mi = 0; mi < 4; ++mi) {
      int row = mw + mi * 16 + fr;
      af[mi] = *(const bf16x8*)&As[cur][(row * 4 + (fg ^ ((row >> 1) & 3))) * 8];
    }
#pragma unroll
    for (int ni = 0; ni < 4; ++ni) {
      int row = nw + ni * 16 + fr;
      bfr[ni] = *(const bf16x8*)&Bs[cur][(row * 4 + (fg ^ ((row >> 1) & 3))) * 8];
    }
#pragma unroll
    for (int mi = 0; mi < 4; ++mi)
#pragma unroll
      for (int ni = 0; ni < 4; ++ni)
        acc[mi][ni] = __builtin_amdgcn_mfma_f32_16x16x32_bf16(af[mi], bfr[ni], acc[mi][ni], 0, 0, 0);
    __syncthreads();
  }
#pragma unroll
  for (int ni = 0; ni < 4; ++ni) {
    long n = n0 + nw + ni * 16 + fr;
    float bs = bias[n];
#pragma unroll
    for (int mi = 0; mi < 4; ++mi) {
      long rbase = m0 + mw + mi * 16 + fg * 4;
#pragma unroll
      for (int q = 0; q < 4; ++q)
        C[(rbase + q) * 4096 + n] = acc[mi][ni][q] + bs;
    }
  }
}

// ============================================================================
// Logits GEMM: n-inner ordering + swapped-operand fx4 epilogue (R14/R15).
// ============================================================================
__global__ __launch_bounds__(256) void k_gemm_bb(const unsigned short* __restrict__ A,
                                                 const unsigned short* __restrict__ Bw,
                                                 const float* __restrict__ bias,
                                                 float* __restrict__ C) {
  __shared__ __align__(16) unsigned short As[2][4096];
  __shared__ __align__(16) unsigned short Bs[2][4096];
  int lid = blockIdx.x;
  int swz = (lid & 7) * 500 + (lid >> 3);   // XCD-chunked (4000 % 8 == 0)
  long m0 = (long)(swz / 250) * 128;        // n inner -> A panel L2-resident
  long n0 = (long)(swz % 250) * 128;
  int tid = threadIdx.x, lane = tid & 63, w = tid >> 6;
  int mw = (w & 1) * 64, nw = (w >> 1) * 64;
  int fr = lane & 15, fg = lane >> 4;
  fx4 acc[4][4] = {};
  int c0 = tid, c1 = tid + 256;
  int r0 = c0 >> 2, k0s = (c0 & 3) ^ ((r0 >> 1) & 3);
  int r1 = c1 >> 2, k1s = (c1 & 3) ^ ((r1 >> 1) & 3);
  const unsigned short* gA0 = A + (m0 + r0) * 1024 + k0s * 8;
  const unsigned short* gA1 = A + (m0 + r1) * 1024 + k1s * 8;
  const unsigned short* gB0 = Bw + (n0 + r0) * 1024 + k0s * 8;
  const unsigned short* gB1 = Bw + (n0 + r1) * 1024 + k1s * 8;
  auto stage = [&](int buf, int kt) {
    int k0 = kt * 32;
    gload_lds16(gA0 + k0, &As[buf][c0 * 8]);
    gload_lds16(gA1 + k0, &As[buf][c1 * 8]);
    gload_lds16(gB0 + k0, &Bs[buf][c0 * 8]);
    gload_lds16(gB1 + k0, &Bs[buf][c1 * 8]);
  };
  stage(0, 0);
  __syncthreads();
  for (int kt = 0; kt < 32; ++kt) {
    int cur = kt & 1;
    if (kt < 31) stage(cur ^ 1, kt + 1);
    bf16x8 af[4], bfr[4];
#pragma unroll
    for (int mi = 0; mi < 4; ++mi) {
      int row = mw + mi * 16 + fr;
      af[mi] = *(const bf16x8*)&As[cur][(row * 4 + (fg ^ ((row >> 1) & 3))) * 8];
    }
#pragma unroll
    for (int ni = 0; ni < 4; ++ni) {
      int row = nw + ni * 16 + fr;
      bfr[ni] = *(const bf16x8*)&Bs[cur][(row * 4 + (fg ^ ((row >> 1) & 3))) * 8];
    }
    // SWAPPED: output fg*4+q indexes n, fr indexes m.
#pragma unroll
    for (int mi = 0; mi < 4; ++mi)
#pragma unroll
      for (int ni = 0; ni < 4; ++ni)
        acc[mi][ni] = __builtin_amdgcn_mfma_f32_16x16x32_bf16(bfr[ni], af[mi], acc[mi][ni], 0, 0, 0);
    __syncthreads();
  }
#pragma unroll
  for (int mi = 0; mi < 4; ++mi) {
    long m = m0 + mw + mi * 16 + fr;
#pragma unroll
    for (int ni = 0; ni < 4; ++ni) {
      long nbase = n0 + nw + ni * 16 + fg * 4;
      fx4 bs4 = *(const fx4*)&bias[nbase];
      fx4 o = { acc[mi][ni][0] + bs4[0], acc[mi][ni][1] + bs4[1],
                acc[mi][ni][2] + bs4[2], acc[mi][ni][3] + bs4[3] };
      *(fx4*)&C[m * 32000 + nbase] = o;
    }
  }
}

// ============================================================================
// Fallback GEMM (reg-staged, B may be fp32 converted in-register).
// ============================================================================
template<typename TA, typename TB>
__global__ __launch_bounds__(256) void k_gemm(const TA* __restrict__ A,
                                              const TB* __restrict__ Bw,
                                              const float* __restrict__ bias,
                                              float* __restrict__ C,
                                              int ldc, int q8) {
  __shared__ __align__(16) unsigned short As[2][4096];
  __shared__ __align__(16) unsigned short Bs[2][4096];
  int lid = blockIdx.x;
  int swz = (lid & 7) * q8 + (lid >> 3);
  long m0 = (long)(swz & 15) * 128;
  long n0 = (long)(swz >> 4) * 128;
  int tid = threadIdx.x, lane = tid & 63, w = tid >> 6;
  int mw = (w & 1) * 64, nw = (w >> 1) * 64;
  int fr = lane & 15, fg = lane >> 4;
  fx4 acc[4][4] = {};

  int crow[2], kc[2], phys[2];
#pragma unroll
  for (int u = 0; u < 2; ++u) {
    int c = tid + u * 256;
    crow[u] = c >> 2; kc[u] = c & 3;
    phys[u] = crow[u] * 4 + (kc[u] ^ ((crow[u] >> 1) & 3));
  }
  u32x4 ra[2], rb[2];
  auto loadOne = [&](const auto* P, long row, int u) -> u32x4 {
    long off = row * 1024 + kc[u] * 8;
    if constexpr (sizeof(*P) == 2) {
      return *(const u32x4*)(P + off);
    } else {
      fx4 lo = *(const fx4*)(P + off);
      fx4 hi = *(const fx4*)(P + off + 4);
      u32x4 r = { pk(lo[0], lo[1]), pk(lo[2], lo[3]), pk(hi[0], hi[1]), pk(hi[2], hi[3]) };
      return r;
    }
  };
  auto loadRegs = [&](int kt) {
#pragma unroll
    for (int u = 0; u < 2; ++u) {
      ra[u] = loadOne(A + (long)kt * 32, m0 + crow[u], u);
      rb[u] = loadOne(Bw + (long)kt * 32, n0 + crow[u], u);
    }
  };
  auto storeRegs = [&](int buf) {
#pragma unroll
    for (int u = 0; u < 2; ++u) {
      *(u32x4*)&As[buf][phys[u] * 8] = ra[u];
      *(u32x4*)&Bs[buf][phys[u] * 8] = rb[u];
    }
  };
  loadRegs(0);
  storeRegs(0);
  __syncthreads();
  for (int kt = 0; kt < 32; ++kt) {
    int cur = kt & 1;
    if (kt < 31) loadRegs(kt + 1);
    bf16x8 af[4], bf_[4];
#pragma unroll
    for (int mi = 0; mi < 4; ++mi) {
      int row = mw + mi * 16 + fr;
      af[mi] = *(const bf16x8*)&As[cur][(row * 4 + (fg ^ ((row >> 1) & 3))) * 8];
    }
#pragma unroll
    for (int ni = 0; ni < 4; ++ni) {
      int row = nw + ni * 16 + fr;
      bf_[ni] = *(const bf16x8*)&Bs[cur][(row * 4 + (fg ^ ((row >> 1) & 3))) * 8];
    }
#pragma unroll
    for (int mi = 0; mi < 4; ++mi)
#pragma unroll
      for (int ni = 0; ni < 4; ++ni)
        acc[mi][ni] = __builtin_amdgcn_mfma_f32_16x16x32_bf16(af[mi], bf_[ni], acc[mi][ni], 0, 0, 0);
    if (kt < 31) storeRegs((kt + 1) & 1);
    __syncthreads();
  }
#pragma unroll
  for (int ni = 0; ni < 4; ++ni) {
    long n = n0 + nw + ni * 16 + fr;
    float bs = bias[n];
#pragma unroll
    for (int mi = 0; mi < 4; ++mi) {
      long rbase = m0 + mw + mi * 16 + fg * 4;
#pragma unroll
      for (int q = 0; q < 4; ++q)
        C[(rbase + q) * ldc + n] = acc[mi][ni][q] + bs;
    }
  }
}

// ---------- in-place row log-softmax, online max+sum (single extra read) ----------
__global__ __launch_bounds__(256) void k_logsoftmax(float* __restrict__ logits) {
  long base = (long)blockIdx.x * 32000;
  float* row = logits + base;
  int tid = threadIdx.x;
  __shared__ float redm[4], reds[4];
  float m = -3.4e38f, s = 0.f;
  for (int i = tid; i < 8000; i += 256) {
    fx4 v = ((const fx4*)row)[i];
    float cm = fmaxf(fmaxf(v[0], v[1]), fmaxf(v[2], v[3]));
    if (cm > m) { s *= __expf(m - cm); m = cm; }
    s += __expf(v[0] - m) + __expf(v[1] - m) + __expf(v[2] - m) + __expf(v[3] - m);
  }
  for (int o = 32; o; o >>= 1) {
    float m2 = __shfl_xor(m, o), s2 = __shfl_xor(s, o);
    float mn = fmaxf(m, m2);
    s = s * __expf(m - mn) + s2 * __expf(m2 - mn);
    m = mn;
  }
  if ((tid & 63) == 0) { redm[tid >> 6] = m; reds[tid >> 6] = s; }
  __syncthreads();
  float M = fmaxf(fmaxf(redm[0], redm[1]), fmaxf(redm[2], redm[3]));
  float S = reds[0] * __expf(redm[0] - M) + reds[1] * __expf(redm[1] - M) +
            reds[2] * __expf(redm[2] - M) + reds[3] * __expf(redm[3] - M);
  float lse = M + logf(S);
  for (int i = tid; i < 8000; i += 256) {
    fx4 v = ((const fx4*)row)[i];
    fx4 o = { v[0] - lse, v[1] - lse, v[2] - lse, v[3] - lse };
    ((fx4*)row)[i] = o;
  }
}

extern "C" void kernel_launch(void* const* d_in, const int* in_sizes, int n_in,
                              void* d_out, int out_size, void* d_ws, size_t ws_size,
                              hipStream_t stream) {
  const int*   x     = (const int*)d_in[0];
  const int*   xmask = (const int*)d_in[1];
  const int*   y     = (const int*)d_in[2];
  const float* h0    = (const float*)d_in[3];
  const float* c0    = (const float*)d_in[4];
  const float* embE  = (const float*)d_in[5];
  const float* embC  = (const float*)d_in[6];
  const float* WihE  = (const float*)d_in[7];
  const float* WhhE  = (const float*)d_in[8];
  const float* bihE  = (const float*)d_in[9];
  const float* bhhE  = (const float*)d_in[10];
  const float* WihD  = (const float*)d_in[11];
  const float* WhhD  = (const float*)d_in[12];
  const float* bihD  = (const float*)d_in[13];
  const float* bhhD  = (const float*)d_in[14];
  const float* Wout  = (const float*)d_in[15];
  const float* bout  = (const float*)d_in[16];

  float* out = (float*)d_out;
  float* decoded = out;                 // [2048][32000] final log-softmax
  float* hiddens = out + 65536000L;     // [32][64][1024] final hiddens

  // Pre-logits scratch inside the decoded region (fully consumed before the
  // logits GEMM overwrites it).
  float* xg_e = decoded;                                    // 8,388,608 f
  float* xg_d = decoded + 8388608L;                         // 8,388,608 f
  unsigned short* xe_bf   = (unsigned short*)(decoded + 16777216L);  // 2,097,152 us
  unsigned short* ye_bf   = xe_bf + 2097152L;                        // 2,097,152 us
  unsigned short* WihE_bf = ye_bf + 2097152L;                        // 4,194,304 us
  unsigned short* WihD_bf = WihE_bf + 4194304L;                      // 4,194,304 us
  char* sp = (char*)(WihD_bf + 4194304L);
  unsigned* hbufT = (unsigned*)sp; sp += 65536 * 4;  // [2][32][1024] tagged u32
  int* sel = (int*)sp; sp += 256;

  // ws: bf16 hiddens b-major (4MB) + bf16 Wout (65.5MB)
  unsigned short* hid_bf  = (unsigned short*)d_ws;
  unsigned short* Wout_bf = hid_bf + 2097152L;
  size_t need1 = 2048L * 1024 * 2;
  size_t need2 = need1 + 32000L * 1024 * 2;
  bool fast1 = ws_size >= need1;
  bool fast2 = ws_size >= need2;

  // init (zero tags + sel), gathers, Wih converts
  k_init<<<64, 256, 0, stream>>>(xmask, sel, hbufT);
  k_gather2<<<4096, 256, 0, stream>>>(embE, x, xe_bf, embC, y, ye_bf);
  k_f2bf_dual<<<2048, 256, 0, stream>>>(WihE, WihE_bf, WihD, WihD_bf, 1048576L);

  // both pre-gate GEMMs in one launch
  k_gemm_dual<<<1024, 256, 0, stream>>>(xe_bf, WihE_bf, bihE, xg_e,
                                        ye_bf, WihD_bf, bihD, xg_d);

  // merged encoder+decoder scan, tagged h exchange (+ Wout convert on spares)
  k_scan_all<<<SCAN_NBLK + (fast2 ? 192 : 0), 512, 0, stream>>>(
      WhhE, bhhE, xg_e, WhhD, bhhD, xg_d, h0, c0, hbufT, sel, hiddens,
      fast1 ? hid_bf : nullptr, Wout, Wout_bf, fast2 ? 8192000L : 0L);

  // logits GEMM + log-softmax, in place in d_out
  if (fast2)      k_gemm_bb<<<4000, 256, 0, stream>>>(hid_bf, Wout_bf, bout, decoded);
  else if (fast1) k_gemm<unsigned short, float><<<4000, 256, 0, stream>>>(hid_bf, Wout, bout, decoded, 32000, 500);
  else            k_gemm<float, float><<<4000, 256, 0, stream>>>(hiddens, Wout, bout, decoded, 32000, 500);
  k_logsoftmax<<<2048, 256, 0, stream>>>(decoded);
}

// Round 17
// 889.210 us; speedup vs baseline: 1.5725x; 1.5725x over previous
//
#include <hip/hip_runtime.h>

typedef __attribute__((ext_vector_type(8))) short bf16x8;
typedef __attribute__((ext_vector_type(4))) float fx4;
typedef __attribute__((ext_vector_type(4))) unsigned short u16x4;
typedef __attribute__((ext_vector_type(8))) unsigned short u16x8;
typedef __attribute__((ext_vector_type(4))) unsigned int u32x4;

#define DEV static __device__ __forceinline__

DEV unsigned short f2bf(float f) {
  union { float f; unsigned u; } v; v.f = f;
  unsigned u = v.u;
  u += 0x7fffu + ((u >> 16) & 1u);
  return (unsigned short)(u >> 16);
}
DEV unsigned pk(float a, float b) { return (unsigned)f2bf(a) | ((unsigned)f2bf(b) << 16); }
DEV float sigm(float x) { return 1.f / (1.f + __expf(-x)); }

// coalesced 16B load bypassing (possibly stale) L1/L2, served at MALL.
DEV u32x4 load_coh16(const void* p) {
  u32x4 r;
  asm volatile("global_load_dwordx4 %0, %1, off sc0 sc1" : "=v"(r) : "v"(p));
  return r;
}

// async global->LDS 16B (m97 staging path)
typedef __attribute__((address_space(1))) const unsigned int guint;
typedef __attribute__((address_space(3))) unsigned int luint;
DEV void gload_lds16(const void* g, void* l) {
  __builtin_amdgcn_global_load_lds((guint*)g, (luint*)l, 16, 0, 0);
}

// ---------- dual embedding gather -> bf16, dst row r = t*32 + b ----------
__global__ void k_gather2(const float* __restrict__ embE, const int* __restrict__ tokE,
                          unsigned short* __restrict__ dstE,
                          const float* __restrict__ embC, const int* __restrict__ tokC,
                          unsigned short* __restrict__ dstC) {
  int bid = blockIdx.x;
  int r = bid & 2047;
  const float* emb = bid < 2048 ? embE : embC;
  const int* tok = bid < 2048 ? tokE : tokC;
  unsigned short* dst = bid < 2048 ? dstE : dstC;
  int t = r >> 5, b = r & 31;
  int token = tok[b * 64 + t];  // tok is [B=32][T=64]
  const fx4* srow = (const fx4*)(emb + (long)token * 1024);
  u16x4* drow = (u16x4*)(dst + (long)r * 1024);
  fx4 v = srow[threadIdx.x];
  u16x4 o = { f2bf(v[0]), f2bf(v[1]), f2bf(v[2]), f2bf(v[3]) };
  drow[threadIdx.x] = o;
}

// ---------- lengths + barrier zero ----------
__global__ void k_lengths(const int* __restrict__ mask, int* __restrict__ sel,
                          int* __restrict__ bar) {
  int t = threadIdx.x;
  for (int i = t; i < 4096; i += 256) bar[i] = 0;
  if (t < 32) {
    int s = 0;
    for (int k = 0; k < 64; ++k) s += mask[t * 64 + k];
    sel[t] = (s + 63) & 63;  // (sum-1) with jnp negative-index wrap
  }
}

// ---------- dual fp32 -> bf16 convert (WihE + WihD) ----------
__global__ void k_f2bf_dual(const float* __restrict__ s0, unsigned short* __restrict__ d0,
                            const float* __restrict__ s1, unsigned short* __restrict__ d1,
                            long n4) {
  const float* s = blockIdx.x < 1024 ? s0 : s1;
  unsigned short* d = blockIdx.x < 1024 ? d0 : d1;
  long base = (long)(blockIdx.x & 1023) * 256 + threadIdx.x;
  for (long i = base; i < n4; i += 1024 * 256) {
    fx4 v = ((const fx4*)s)[i];
    u16x4 o = { f2bf(v[0]), f2bf(v[1]), f2bf(v[2]), f2bf(v[3]) };
    ((u16x4*)d)[i] = o;
  }
}

// ============================================================================
// Persistent LSTM scan. 64 scan blocks x 512 threads, 1 block/CU (104 KB LDS).
// Block owns 16 j's (j0 XCD-swizzled). 64 Whh rows in REGISTERS (32 x bf16x8
// per wave). 8 waves = 2 batch-halves x 4 gate-tiles, full K per wave.
// h staged to LDS via sc0/sc1 coalesced loads. 64 monotone flags 128B apart;
// wave0 polls one flag per lane. Enc gens 1..63, dec gens 65..127.
// Blocks >=64 (MODE 0): Wout fp32->bf16 convert on idle CUs, then retire.
// ============================================================================
#define SCAN_NBLK 64

template<int MODE>  // 0 = encoder (save h,c at t==sel[b]); 1 = decoder (emit hiddens)
__global__ __launch_bounds__(512) void k_scan(
    const float* __restrict__ Whh,        // [4096][1024] fp32
    const float* __restrict__ bhh,        // [4096]
    const float* __restrict__ xg,         // [64][32][4096] fp32
    const float* __restrict__ hinit,      // [32][1024] fp32 (h0 or hsel)
    const float* __restrict__ cinit,      // [32][1024] fp32 (c0 or csel)
    unsigned short* __restrict__ hbuf,    // [2][32][1024] bf16 double buffer
    const int* __restrict__ sel,
    float* __restrict__ hsel, float* __restrict__ csel,
    float* __restrict__ hid_out,          // [32][64][1024] fp32 (decoder)
    unsigned short* __restrict__ hid_bf,  // [2048][1024] bf16 b-major (decoder)
    int* __restrict__ bar,
    const float* __restrict__ wsrc,       // MODE0: convert source
    unsigned short* __restrict__ wdst,    // MODE0: convert dest
    long wn4) {
  int tid = threadIdx.x;
  int bid = blockIdx.x;
  if (bid >= SCAN_NBLK) {  // spare blocks: Wout convert on idle CUs, then exit
    long i = (long)(bid - SCAN_NBLK) * 512 + tid;
    long st = (long)(gridDim.x - SCAN_NBLK) * 512;
    for (; i < wn4; i += st) {
      fx4 v = ((const fx4*)wsrc)[i];
      u16x4 o = { f2bf(v[0]), f2bf(v[1]), f2bf(v[2]), f2bf(v[3]) };
      ((u16x4*)wdst)[i] = o;
    }
    return;
  }
  __shared__ __align__(16) unsigned short hlds[49152];  // 96 KB decl (64 used)
  __shared__ float gbuf[4][32][16];                     // 8 KB
  int j0 = ((bid & 7) * 8 + (bid >> 3)) * 16;  // XCD-contiguous 128-j band
  int w = tid >> 6, lane = tid & 63;
  int mt = w & 1, nt = w >> 1;          // batch half (2) x gate tile (4)
  int fr = lane & 15, fg = lane >> 4;
  unsigned* hbU = (unsigned*)hbuf;
  constexpr int GBASE = MODE ? 64 : 0;

  // ---- one-time: this wave's Whh fragments into registers (fp32->bf16)
  bf16x8 breg[32];
  {
    const float* wrow = Whh + ((long)(nt * 1024 + j0 + fr) << 10);
#pragma unroll
    for (int i = 0; i < 32; ++i) {
      int kc = i * 4 + fg;
      fx4 lo = *(const fx4*)(wrow + kc * 8);
      fx4 hi = *(const fx4*)(wrow + kc * 8 + 4);
      bf16x8 o = { (short)f2bf(lo[0]), (short)f2bf(lo[1]), (short)f2bf(lo[2]), (short)f2bf(lo[3]),
                   (short)f2bf(hi[0]), (short)f2bf(hi[1]), (short)f2bf(hi[2]), (short)f2bf(hi[3]) };
      breg[i] = o;
    }
  }

  // ---- per-thread state: 512 threads = 32 b x 16 j ----
  int b = tid >> 4, jj = tid & 15, j = j0 + jj;
  float bh0 = bhh[j], bh1 = bhh[1024 + j], bh2 = bhh[2048 + j], bh3 = bhh[3072 + j];
  float c_reg = cinit[b * 1024 + j];
  int sel_b = (MODE == 0) ? sel[b] : -1;
  const float* xp0 = xg + (long)b * 4096 + j;
  float x0 = xp0[0], x1 = xp0[1024], x2 = xp0[2048], x3 = xp0[3072];

  for (int t = 0; t < 64; ++t) {
    // ---- stage h (64 KB bf16) into LDS, rows = b, 128 chunks of 16B ----
    if (t == 0) {
#pragma unroll
      for (int it = 0; it < 8; ++it) {
        int c = it * 512 + tid;
        const float* src = hinit + (long)c * 8;
        fx4 lo = *(const fx4*)src;
        fx4 hi = *(const fx4*)(src + 4);
        int row = c >> 7, kc = c & 127;
        u16x8 o = { f2bf(lo[0]), f2bf(lo[1]), f2bf(lo[2]), f2bf(lo[3]),
                    f2bf(hi[0]), f2bf(hi[1]), f2bf(hi[2]), f2bf(hi[3]) };
        *(u16x8*)&hlds[(row * 128 + (kc ^ (row & 31))) * 8] = o;
      }
    } else {
      const char* hsrc = (const char*)hbuf + (t & 1) * 65536;
      u32x4 hv[8];
#pragma unroll
      for (int it = 0; it < 8; ++it) {
        int c = it * 512 + tid;
        hv[it] = load_coh16(hsrc + (long)c * 16);
      }
      asm volatile("s_waitcnt vmcnt(0)" ::: "memory");
      __builtin_amdgcn_sched_barrier(0);
#pragma unroll
      for (int it = 0; it < 8; ++it) {
        int c = it * 512 + tid;
        int row = c >> 7, kc = c & 127;
        *(u16x8*)&hlds[(row * 128 + (kc ^ (row & 31))) * 8] = *(u16x8*)&hv[it];
      }
    }
    __syncthreads();

    // ---- gate GEMM: A-frags from hlds, B-frags from registers, full K ----
    int arow = mt * 16 + fr;
    fx4 acca = {0.f, 0.f, 0.f, 0.f}, accb = {0.f, 0.f, 0.f, 0.f};
#pragma unroll
    for (int i = 0; i < 32; i += 2) {
      int kcA = i * 4 + fg;
      int kcB = (i + 1) * 4 + fg;
      bf16x8 a0 = *(const bf16x8*)&hlds[(arow * 128 + (kcA ^ (arow & 31))) * 8];
      bf16x8 a1 = *(const bf16x8*)&hlds[(arow * 128 + (kcB ^ (arow & 31))) * 8];
      acca = __builtin_amdgcn_mfma_f32_16x16x32_bf16(a0, breg[i], acca, 0, 0, 0);
      accb = __builtin_amdgcn_mfma_f32_16x16x32_bf16(a1, breg[i + 1], accb, 0, 0, 0);
    }
#pragma unroll
    for (int q = 0; q < 4; ++q)
      gbuf[nt][mt * 16 + fg * 4 + q][fr] = acca[q] + accb[q];
    __syncthreads();

    // ---- gate nonlinearity + state update (all 512 threads: 32 b x 16 j) ----
    {
      float gi = gbuf[0][b][jj] + bh0 + x0;
      float gf = gbuf[1][b][jj] + bh1 + x1;
      float gg = gbuf[2][b][jj] + bh2 + x2;
      float go = gbuf[3][b][jj] + bh3 + x3;
      float c_new = sigm(gf) * c_reg + sigm(gi) * tanhf(gg);
      float h = sigm(go) * tanhf(c_new);
      c_reg = c_new;
      float hp = __shfl_xor(h, 1);
      if ((jj & 1) == 0) {
        unsigned val = pk(h, hp);
        __hip_atomic_store(&hbU[((t & 1) ^ 1) * 16384 + b * 512 + ((j0 + jj) >> 1)], val,
                           __ATOMIC_RELAXED, __HIP_MEMORY_SCOPE_AGENT);
      }
      if (MODE == 0) {
        if (t == sel_b) { hsel[b * 1024 + j] = h; csel[b * 1024 + j] = c_new; }
      } else {
        long o = ((long)b * 64 + t) * 1024 + j;
        hid_out[o] = h;
        if (hid_bf) hid_bf[o] = f2bf(h);  // plain store; read next kernel
      }
    }

    if (t < 63) {
      // prefetch next step's xg (latency hides under the barrier)
      const float* xp = xg + (long)(t + 1) * 131072 + (long)b * 4096 + j;
      float nx0 = xp[0], nx1 = xp[1024], nx2 = xp[2048], nx3 = xp[3072];
      __syncthreads();  // drains vmcnt -> this block's h stores are MALL-visible
      if (w == 0) {
        if (lane == 0)
          __hip_atomic_store(&bar[bid * 32], GBASE + t + 1, __ATOMIC_RELAXED, __HIP_MEMORY_SCOPE_AGENT);
        int want = GBASE + t + 1;
        for (;;) {
          int v0 = __hip_atomic_load(&bar[lane * 32], __ATOMIC_RELAXED, __HIP_MEMORY_SCOPE_AGENT);
          if (__ballot(v0 >= want) == 0xFFFFFFFFFFFFFFFFULL) break;
          __builtin_amdgcn_s_sleep(1);
        }
      }
      __syncthreads();
      x0 = nx0; x1 = nx1; x2 = nx2; x3 = nx3;
    }
  }
}

// ============================================================================
// Dual pre-gate GEMM (m97 + both-sides swizzle): blocks 0..511 -> set 0,
// 512..1023 -> set 1.
// ============================================================================
__global__ __launch_bounds__(256) void k_gemm_dual(
    const unsigned short* __restrict__ A0, const unsigned short* __restrict__ B0,
    const float* __restrict__ bias0, float* __restrict__ C0,
    const unsigned short* __restrict__ A1, const unsigned short* __restrict__ B1,
    const float* __restrict__ bias1, float* __restrict__ C1) {
  __shared__ __align__(16) unsigned short As[2][4096];
  __shared__ __align__(16) unsigned short Bs[2][4096];
  int lid = blockIdx.x;
  int half = lid >> 9, l = lid & 511;
  const unsigned short* A = half ? A1 : A0;
  const unsigned short* Bw = half ? B1 : B0;
  const float* bias = half ? bias1 : bias0;
  float* C = half ? C1 : C0;
  int swz = (l & 7) * 64 + (l >> 3);
  long m0 = (long)(swz & 15) * 128;
  long n0 = (long)(swz >> 4) * 128;
  int tid = threadIdx.x, lane = tid & 63, w = tid >> 6;
  int mw = (w & 1) * 64, nw = (w >> 1) * 64;
  int fr = lane & 15, fg = lane >> 4;
  fx4 acc[4][4] = {};
  int c0 = tid, c1 = tid + 256;
  int r0 = c0 >> 2, k0s = (c0 & 3) ^ ((r0 >> 1) & 3);
  int r1 = c1 >> 2, k1s = (c1 & 3) ^ ((r1 >> 1) & 3);
  const unsigned short* gA0 = A + (m0 + r0) * 1024 + k0s * 8;
  const unsigned short* gA1 = A + (m0 + r1) * 1024 + k1s * 8;
  const unsigned short* gB0 = Bw + (n0 + r0) * 1024 + k0s * 8;
  const unsigned short* gB1 = Bw + (n0 + r1) * 1024 + k1s * 8;
  auto stage = [&](int buf, int kt) {
    int k0 = kt * 32;
    gload_lds16(gA0 + k0, &As[buf][c0 * 8]);
    gload_lds16(gA1 + k0, &As[buf][c1 * 8]);
    gload_lds16(gB0 + k0, &Bs[buf][c0 * 8]);
    gload_lds16(gB1 + k0, &Bs[buf][c1 * 8]);
  };
  stage(0, 0);
  __syncthreads();
  for (int kt = 0; kt < 32; ++kt) {
    int cur = kt & 1;
    if (kt < 31) stage(cur ^ 1, kt + 1);
    bf16x8 af[4], bfr[4];
#pragma unroll
    for (int mi = 0; mi < 4; ++mi) {
      int row = mw + mi * 16 + fr;
      af[mi] = *(const bf16x8*)&As[cur][(row * 4 + (fg ^ ((row >> 1) & 3))) * 8];
    }
#pragma unroll
    for (int ni = 0; ni < 4; ++ni) {
      int row = nw + ni * 16 + fr;
      bfr[ni] = *(const bf16x8*)&Bs[cur][(row * 4 + (fg ^ ((row >> 1) & 3))) * 8];
    }
#pragma unroll
    for (int mi = 0; mi < 4; ++mi)
#pragma unroll
      for (int ni = 0; ni < 4; ++ni)
        acc[mi][ni] = __builtin_amdgcn_mfma_f32_16x16x32_bf16(af[mi], bfr[ni], acc[mi][ni], 0, 0, 0);
    __syncthreads();
  }
#pragma unroll
  for (int ni = 0; ni < 4; ++ni) {
    long n = n0 + nw + ni * 16 + fr;
    float bs = bias[n];
#pragma unroll
    for (int mi = 0; mi < 4; ++mi) {
      long rbase = m0 + mw + mi * 16 + fg * 4;
#pragma unroll
      for (int q = 0; q < 4; ++q)
        C[(rbase + q) * 4096 + n] = acc[mi][ni][q] + bs;
    }
  }
}

// ============================================================================
// Logits GEMM (m97 + both-sides swizzle, m-inner, plain epilogue — R12 best).
// M=2048 N=32000 K=1024, grid 4000, q8=500.
// ============================================================================
__global__ __launch_bounds__(256) void k_gemm_bb(const unsigned short* __restrict__ A,
                                                 const unsigned short* __restrict__ Bw,
                                                 const float* __restrict__ bias,
                                                 float* __restrict__ C) {
  __shared__ __align__(16) unsigned short As[2][4096];
  __shared__ __align__(16) unsigned short Bs[2][4096];
  int lid = blockIdx.x;
  int swz = (lid & 7) * 500 + (lid >> 3);   // XCD-chunked (4000 % 8 == 0)
  long m0 = (long)(swz & 15) * 128;         // m inner -> B-panel L2 reuse
  long n0 = (long)(swz >> 4) * 128;
  int tid = threadIdx.x, lane = tid & 63, w = tid >> 6;
  int mw = (w & 1) * 64, nw = (w >> 1) * 64;
  int fr = lane & 15, fg = lane >> 4;
  fx4 acc[4][4] = {};
  int c0 = tid, c1 = tid + 256;
  int r0 = c0 >> 2, k0s = (c0 & 3) ^ ((r0 >> 1) & 3);
  int r1 = c1 >> 2, k1s = (c1 & 3) ^ ((r1 >> 1) & 3);
  const unsigned short* gA0 = A + (m0 + r0) * 1024 + k0s * 8;
  const unsigned short* gA1 = A + (m0 + r1) * 1024 + k1s * 8;
  const unsigned short* gB0 = Bw + (n0 + r0) * 1024 + k0s * 8;
  const unsigned short* gB1 = Bw + (n0 + r1) * 1024 + k1s * 8;
  auto stage = [&](int buf, int kt) {
    int k0 = kt * 32;
    gload_lds16(gA0 + k0, &As[buf][c0 * 8]);
    gload_lds16(gA1 + k0, &As[buf][c1 * 8]);
    gload_lds16(gB0 + k0, &Bs[buf][c0 * 8]);
    gload_lds16(gB1 + k0, &Bs[buf][c1 * 8]);
  };
  stage(0, 0);
  __syncthreads();
  for (int kt = 0; kt < 32; ++kt) {
    int cur = kt & 1;
    if (kt < 31) stage(cur ^ 1, kt + 1);
    bf16x8 af[4], bfr[4];
#pragma unroll
    for (int mi = 0; mi < 4; ++mi) {
      int row = mw + mi * 16 + fr;
      af[mi] = *(const bf16x8*)&As[cur][(row * 4 + (fg ^ ((row >> 1) & 3))) * 8];
    }
#pragma unroll
    for (int ni = 0; ni < 4; ++ni) {
      int row = nw + ni * 16 + fr;
      bfr[ni] = *(const bf16x8*)&Bs[cur][(row * 4 + (fg ^ ((row >> 1) & 3))) * 8];
    }
#pragma unroll
    for (int mi = 0; mi < 4; ++mi)
#pragma unroll
      for (int ni = 0; ni < 4; ++ni)
        acc[mi][ni] = __builtin_amdgcn_mfma_f32_16x16x32_bf16(af[mi], bfr[ni], acc[mi][ni], 0, 0, 0);
    __syncthreads();
  }
#pragma unroll
  for (int ni = 0; ni < 4; ++ni) {
    long n = n0 + nw + ni * 16 + fr;
    float bs = bias[n];
#pragma unroll
    for (int mi = 0; mi < 4; ++mi) {
      long rbase = m0 + mw + mi * 16 + fg * 4;
#pragma unroll
      for (int q = 0; q < 4; ++q)
        C[(rbase + q) * 32000 + n] = acc[mi][ni][q] + bs;
    }
  }
}

// ============================================================================
// Fallback GEMM (reg-staged, B may be fp32 converted in-register).
// ============================================================================
template<typename TA, typename TB>
__global__ __launch_bounds__(256) void k_gemm(const TA* __restrict__ A,
                                              const TB* __restrict__ Bw,
                                              const float* __restrict__ bias,
                                              float* __restrict__ C,
                                              int ldc, int q8) {
  __shared__ __align__(16) unsigned short As[2][4096];
  __shared__ __align__(16) unsigned short Bs[2][4096];
  int lid = blockIdx.x;
  int swz = (lid & 7) * q8 + (lid >> 3);
  long m0 = (long)(swz & 15) * 128;
  long n0 = (long)(swz >> 4) * 128;
  int tid = threadIdx.x, lane = tid & 63, w = tid >> 6;
  int mw = (w & 1) * 64, nw = (w >> 1) * 64;
  int fr = lane & 15, fg = lane >> 4;
  fx4 acc[4][4] = {};

  int crow[2], kc[2], phys[2];
#pragma unroll
  for (int u = 0; u < 2; ++u) {
    int c = tid + u * 256;
    crow[u] = c >> 2; kc[u] = c & 3;
    phys[u] = crow[u] * 4 + (kc[u] ^ ((crow[u] >> 1) & 3));
  }
  u32x4 ra[2], rb[2];
  auto loadOne = [&](const auto* P, long row, int u) -> u32x4 {
    long off = row * 1024 + kc[u] * 8;
    if constexpr (sizeof(*P) == 2) {
      return *(const u32x4*)(P + off);
    } else {
      fx4 lo = *(const fx4*)(P + off);
      fx4 hi = *(const fx4*)(P + off + 4);
      u32x4 r = { pk(lo[0], lo[1]), pk(lo[2], lo[3]), pk(hi[0], hi[1]), pk(hi[2], hi[3]) };
      return r;
    }
  };
  auto loadRegs = [&](int kt) {
#pragma unroll
    for (int u = 0; u < 2; ++u) {
      ra[u] = loadOne(A + (long)kt * 32, m0 + crow[u], u);
      rb[u] = loadOne(Bw + (long)kt * 32, n0 + crow[u], u);
    }
  };
  auto storeRegs = [&](int buf) {
#pragma unroll
    for (int u = 0; u < 2; ++u) {
      *(u32x4*)&As[buf][phys[u] * 8] = ra[u];
      *(u32x4*)&Bs[buf][phys[u] * 8] = rb[u];
    }
  };
  loadRegs(0);
  storeRegs(0);
  __syncthreads();
  for (int kt = 0; kt < 32; ++kt) {
    int cur = kt & 1;
    if (kt < 31) loadRegs(kt + 1);
    bf16x8 af[4], bf_[4];
#pragma unroll
    for (int mi = 0; mi < 4; ++mi) {
      int row = mw + mi * 16 + fr;
      af[mi] = *(const bf16x8*)&As[cur][(row * 4 + (fg ^ ((row >> 1) & 3))) * 8];
    }
#pragma unroll
    for (int ni = 0; ni < 4; ++ni) {
      int row = nw + ni * 16 + fr;
      bf_[ni] = *(const bf16x8*)&Bs[cur][(row * 4 + (fg ^ ((row >> 1) & 3))) * 8];
    }
#pragma unroll
    for (int mi = 0; mi < 4; ++mi)
#pragma unroll
      for (int ni = 0; ni < 4; ++ni)
        acc[mi][ni] = __builtin_amdgcn_mfma_f32_16x16x32_bf16(af[mi], bf_[ni], acc[mi][ni], 0, 0, 0);
    if (kt < 31) storeRegs((kt + 1) & 1);
    __syncthreads();
  }
#pragma unroll
  for (int ni = 0; ni < 4; ++ni) {
    long n = n0 + nw + ni * 16 + fr;
    float bs = bias[n];
#pragma unroll
    for (int mi = 0; mi < 4; ++mi) {
      long rbase = m0 + mw + mi * 16 + fg * 4;
#pragma unroll
      for (int q = 0; q < 4; ++q)
        C[(rbase + q) * ldc + n] = acc[mi][ni][q] + bs;
    }
  }
}

// ---------- in-place row log-softmax, online max+sum (single extra read) ----------
__global__ __launch_bounds__(256) void k_logsoftmax(float* __restrict__ logits) {
  long base = (long)blockIdx.x * 32000;
  float* row = logits + base;
  int tid = threadIdx.x;
  __shared__ float redm[4], reds[4];
  float m = -3.4e38f, s = 0.f;
  for (int i = tid; i < 8000; i += 256) {
    fx4 v = ((const fx4*)row)[i];
    float cm = fmaxf(fmaxf(v[0], v[1]), fmaxf(v[2], v[3]));
    if (cm > m) { s *= __expf(m - cm); m = cm; }
    s += __expf(v[0] - m) + __expf(v[1] - m) + __expf(v[2] - m) + __expf(v[3] - m);
  }
  for (int o = 32; o; o >>= 1) {
    float m2 = __shfl_xor(m, o), s2 = __shfl_xor(s, o);
    float mn = fmaxf(m, m2);
    s = s * __expf(m - mn) + s2 * __expf(m2 - mn);
    m = mn;
  }
  if ((tid & 63) == 0) { redm[tid >> 6] = m; reds[tid >> 6] = s; }
  __syncthreads();
  float M = fmaxf(fmaxf(redm[0], redm[1]), fmaxf(redm[2], redm[3]));
  float S = reds[0] * __expf(redm[0] - M) + reds[1] * __expf(redm[1] - M) +
            reds[2] * __expf(redm[2] - M) + reds[3] * __expf(redm[3] - M);
  float lse = M + logf(S);
  for (int i = tid; i < 8000; i += 256) {
    fx4 v = ((const fx4*)row)[i];
    fx4 o = { v[0] - lse, v[1] - lse, v[2] - lse, v[3] - lse };
    ((fx4*)row)[i] = o;
  }
}

extern "C" void kernel_launch(void* const* d_in, const int* in_sizes, int n_in,
                              void* d_out, int out_size, void* d_ws, size_t ws_size,
                              hipStream_t stream) {
  const int*   x     = (const int*)d_in[0];
  const int*   xmask = (const int*)d_in[1];
  const int*   y     = (const int*)d_in[2];
  const float* h0    = (const float*)d_in[3];
  const float* c0    = (const float*)d_in[4];
  const float* embE  = (const float*)d_in[5];
  const float* embC  = (const float*)d_in[6];
  const float* WihE  = (const float*)d_in[7];
  const float* WhhE  = (const float*)d_in[8];
  const float* bihE  = (const float*)d_in[9];
  const float* bhhE  = (const float*)d_in[10];
  const float* WihD  = (const float*)d_in[11];
  const float* WhhD  = (const float*)d_in[12];
  const float* bihD  = (const float*)d_in[13];
  const float* bhhD  = (const float*)d_in[14];
  const float* Wout  = (const float*)d_in[15];
  const float* bout  = (const float*)d_in[16];

  float* out = (float*)d_out;
  float* decoded = out;                 // [2048][32000] final log-softmax
  float* hiddens = out + 65536000L;     // [32][64][1024] final hiddens

  // Pre-logits scratch inside the decoded region (fully consumed before the
  // logits GEMM overwrites it).
  float* xg_e = decoded;                                    // 8,388,608 f
  float* xg_d = decoded + 8388608L;                         // 8,388,608 f
  unsigned short* xe_bf   = (unsigned short*)(decoded + 16777216L);  // 2,097,152 us
  unsigned short* ye_bf   = xe_bf + 2097152L;                        // 2,097,152 us
  unsigned short* WihE_bf = ye_bf + 2097152L;                        // 4,194,304 us
  unsigned short* WihD_bf = WihE_bf + 4194304L;                      // 4,194,304 us
  char* sp = (char*)(WihD_bf + 4194304L);
  unsigned short* hbuf = (unsigned short*)sp; sp += 2 * 32768 * 2;   // 16B-aligned
  float* hsel = (float*)sp; sp += 32768 * 4;
  float* csel = (float*)sp; sp += 32768 * 4;
  int* sel = (int*)sp; sp += 256;
  int* bar = (int*)sp; sp += 16384;  // 64 flags, 128B apart (zeroed by k_lengths)

  // ws: bf16 hiddens b-major (4MB) + bf16 Wout (65.5MB)
  unsigned short* hid_bf  = (unsigned short*)d_ws;
  unsigned short* Wout_bf = hid_bf + 2097152L;
  size_t need1 = 2048L * 1024 * 2;
  size_t need2 = need1 + 32000L * 1024 * 2;
  bool fast1 = ws_size >= need1;
  bool fast2 = ws_size >= need2;

  // gathers + lengths/bar-zero + Wih converts
  k_gather2<<<4096, 256, 0, stream>>>(embE, x, xe_bf, embC, y, ye_bf);
  k_lengths<<<1, 256, 0, stream>>>(xmask, sel, bar);
  k_f2bf_dual<<<2048, 256, 0, stream>>>(WihE, WihE_bf, WihD, WihD_bf, 1048576L);

  // both pre-gate GEMMs in one launch
  k_gemm_dual<<<1024, 256, 0, stream>>>(xe_bf, WihE_bf, bihE, xg_e,
                                        ye_bf, WihD_bf, bihD, xg_d);

  // encoder scan (+ Wout convert on spare CUs; spares retire, no deadlock risk)
  k_scan<0><<<SCAN_NBLK + (fast2 ? 192 : 0), 512, 0, stream>>>(
      WhhE, bhhE, xg_e, h0, c0, hbuf, sel, hsel, csel, nullptr, nullptr, bar,
      Wout, Wout_bf, fast2 ? 8192000L : 0L);
  // decoder scan
  k_scan<1><<<SCAN_NBLK, 512, 0, stream>>>(
      WhhD, bhhD, xg_d, hsel, csel, hbuf, nullptr, nullptr, nullptr, hiddens,
      fast1 ? hid_bf : nullptr, bar, nullptr, nullptr, 0L);

  // logits GEMM + log-softmax, in place in d_out
  if (fast2)      k_gemm_bb<<<4000, 256, 0, stream>>>(hid_bf, Wout_bf, bout, decoded);
  else if (fast1) k_gemm<unsigned short, float><<<4000, 256, 0, stream>>>(hid_bf, Wout, bout, decoded, 32000, 500);
  else            k_gemm<float, float><<<4000, 256, 0, stream>>>(hiddens, Wout, bout, decoded, 32000, 500);
  k_logsoftmax<<<2048, 256, 0, stream>>>(decoded);
}